// Round 1
// baseline (545.632 us; speedup 1.0000x reference)
//
#include <hip/hip_runtime.h>

#define TT 512
#define BB 64
#define HH 5
#define DD 512
#define NPOS 1023  // 2T-1

typedef __bf16 bf16x8 __attribute__((ext_vector_type(8)));
typedef float floatx4 __attribute__((ext_vector_type(4)));

// ---------- prep: transpose+convert weights to bf16, padded ----------
// WlmT: [192][512] (cols 180..191 zero), WamT: [160][512]
__global__ void prep_w_kernel(const float* __restrict__ Wlm, const float* __restrict__ Wam,
                              __bf16* __restrict__ WlmT, __bf16* __restrict__ WamT) {
  int idx = blockIdx.x * 256 + threadIdx.x;
  if (idx < 192 * 512) {
    int n = idx >> 9, k = idx & 511;
    float v = (n < 180) ? Wlm[k * 180 + n] : 0.f;
    WlmT[idx] = (__bf16)v;
  }
  if (idx < 160 * 512) {
    int n = idx >> 9, k = idx & 511;
    WamT[idx] = (__bf16)Wam[k * 160 + n];
  }
}

// ---------- pe = pos_emb[0] @ W_pos, stored [H][1023][4] fp32 ----------
__global__ void pe_proj_kernel(const float* __restrict__ pos_emb, const float* __restrict__ Wpos,
                               float* __restrict__ peT) {
  int n = blockIdx.x;  // 0..1022
  __shared__ float row[192];
  for (int i = threadIdx.x; i < 192; i += 64) row[i] = pos_emb[n * 192 + i];
  __syncthreads();
  int c = threadIdx.x;
  if (c < 20) {
    float acc = 0.f;
    for (int pd = 0; pd < 192; ++pd) acc += row[pd] * Wpos[pd * 20 + c];
    int h = c >> 2, d = c & 3;
    peT[((size_t)h * NPOS + n) * 4 + d] = acc;
  }
}

// ---------- projection GEMM: (32768 x 512) @ (512 x NT*16) ----------
// A rows m = t*B + b. Outputs: qk bf16 [m][160] (+ p fp32 [m][20] for lm).
template <int NT, bool IS_LM>
__global__ __launch_bounds__(256) void proj_kernel(
    const float* __restrict__ A, const __bf16* __restrict__ WT, const float* __restrict__ bias,
    __bf16* __restrict__ qk_out, float* __restrict__ p_out) {
  __shared__ __align__(16) __bf16 a_lds[64][32];
  __shared__ __align__(16) __bf16 w_lds[NT * 16][32];
  const int tid = threadIdx.x;
  const int m0 = blockIdx.x * 64;
  const int lane = tid & 63, w = tid >> 6;
  const int quad = lane >> 4, nl = lane & 15;

  floatx4 zero = {0.f, 0.f, 0.f, 0.f};
  floatx4 acc[NT];
#pragma unroll
  for (int j = 0; j < NT; ++j) acc[j] = zero;

  const int arow = tid >> 2, aseg = tid & 3;
  for (int k0 = 0; k0 < 512; k0 += 32) {
    // stage A tile 64x32 (f32 -> bf16)
    const float* ap = A + (size_t)(m0 + arow) * 512 + k0 + aseg * 8;
    float4 av0 = *(const float4*)ap;
    float4 av1 = *(const float4*)(ap + 4);
    __bf16* ad = &a_lds[arow][aseg * 8];
    ad[0] = (__bf16)av0.x; ad[1] = (__bf16)av0.y; ad[2] = (__bf16)av0.z; ad[3] = (__bf16)av0.w;
    ad[4] = (__bf16)av1.x; ad[5] = (__bf16)av1.y; ad[6] = (__bf16)av1.z; ad[7] = (__bf16)av1.w;
    // stage W tile (already bf16, [n][512] layout -> w_lds[n][k])
    for (int task = tid; task < NT * 64; task += 256) {
      int n = task >> 2, seg = task & 3;
      *(bf16x8*)&w_lds[n][seg * 8] = *(const bf16x8*)(WT + (size_t)n * 512 + k0 + seg * 8);
    }
    __syncthreads();
    bf16x8 af = *(const bf16x8*)&a_lds[16 * w + nl][quad * 8];
#pragma unroll
    for (int jt = 0; jt < NT; ++jt) {
      bf16x8 bfr = *(const bf16x8*)&w_lds[jt * 16 + nl][quad * 8];
      acc[jt] = __builtin_amdgcn_mfma_f32_16x16x32_bf16(af, bfr, acc[jt], 0, 0, 0);
    }
    __syncthreads();
  }
  // epilogue
#pragma unroll
  for (int jt = 0; jt < NT; ++jt) {
    int c = jt * 16 + nl;
#pragma unroll
    for (int r = 0; r < 4; ++r) {
      int m = m0 + 16 * w + quad * 4 + r;
      float bv;
      if (IS_LM) bv = (c < 180) ? bias[c] : 0.f;
      else bv = bias[c];
      float val = acc[jt][r] + bv;
      if (IS_LM) {
        if (c < 160) qk_out[(size_t)m * 160 + c] = (__bf16)val;
        else if (c < 180) p_out[(size_t)m * 20 + (c - 160)] = val;
      } else {
        qk_out[(size_t)m * 160 + c] = (__bf16)val;
      }
    }
  }
}

// ---------- fused scores + rel-shift + mask + softmax ----------
// grid (8, 64, 5): t-tile of 64, b, h. block 256 = 4 waves, each wave 16 rows x 512 cols.
__global__ __launch_bounds__(256) void attn_kernel(
    const __bf16* __restrict__ q, const __bf16* __restrict__ k,
    const float* __restrict__ p, const float* __restrict__ peT,
    const unsigned char* __restrict__ mask, float* __restrict__ out) {
  __shared__ __align__(16) __bf16 k_lds[512][32];
  __shared__ __align__(16) __bf16 q_lds[64][32];
  __shared__ __align__(16) float p_lds[64][4];
  __shared__ __align__(16) float pe_lds[575 * 4];
  __shared__ float mask_lds[512];

  const int tid = threadIdx.x;
  const int t0 = blockIdx.x * 64;
  const int b = blockIdx.y;
  const int h = blockIdx.z;
  const int lane = tid & 63, w = tid >> 6;
  const int quad = lane >> 4, nl = lane & 15;

  // stage K: 512 rows x 32 bf16 = 32 KB
#pragma unroll
  for (int it = 0; it < 8; ++it) {
    int idx = tid + it * 256;
    int s = idx >> 2, c = idx & 3;
    *(bf16x8*)&k_lds[s][c * 8] =
        *(const bf16x8*)(k + ((size_t)(s * BB + b) * HH + h) * 32 + c * 8);
  }
  // stage Q tile
  {
    int s = tid >> 2, c = tid & 3;
    *(bf16x8*)&q_lds[s][c * 8] =
        *(const bf16x8*)(q + ((size_t)((t0 + s) * BB + b) * HH + h) * 32 + c * 8);
  }
  if (tid < 64) {
    *(float4*)&p_lds[tid][0] =
        *(const float4*)(p + ((size_t)((t0 + tid) * BB + b) * HH + h) * 4);
  }
  {
    int u0 = 448 - t0;  // min u = s - t + 511 for this tile; width 575
    for (int i = tid; i < 575; i += 256)
      *(float4*)&pe_lds[i * 4] = *(const float4*)(peT + ((size_t)h * NPOS + u0 + i) * 4);
  }
  for (int i = tid; i < 512; i += 256)
    mask_lds[i] = mask[b * 512 + i] ? -1000.f : 0.f;
  __syncthreads();

  floatx4 zero = {0.f, 0.f, 0.f, 0.f};
  floatx4 acc[32];
  bf16x8 af = *(const bf16x8*)&q_lds[16 * w + nl][quad * 8];
#pragma unroll
  for (int jt = 0; jt < 32; ++jt) {
    bf16x8 bfr = *(const bf16x8*)&k_lds[jt * 16 + nl][quad * 8];
    acc[jt] = __builtin_amdgcn_mfma_f32_16x16x32_bf16(af, bfr, zero, 0, 0, 0);
  }

  float rmax[4], rinv[4];
#pragma unroll
  for (int r = 0; r < 4; ++r) {
    int tl = 16 * w + quad * 4 + r;
    floatx4 pv = *(const floatx4*)&p_lds[tl][0];
    float mx = -3.4e38f;
#pragma unroll
    for (int jt = 0; jt < 32; ++jt) {
      int s = jt * 16 + nl;
      floatx4 pe = *(const floatx4*)&pe_lds[(s - tl + 63) * 4];
      float v = acc[jt][r] + pv[0] * pe[0] + pv[1] * pe[1] + pv[2] * pe[2] + pv[3] * pe[3] +
                mask_lds[s];
      acc[jt][r] = v;
      mx = fmaxf(mx, v);
    }
#pragma unroll
    for (int d = 1; d < 16; d <<= 1) mx = fmaxf(mx, __shfl_xor(mx, d, 64));
    rmax[r] = mx;
  }
#pragma unroll
  for (int r = 0; r < 4; ++r) {
    float sum = 0.f;
#pragma unroll
    for (int jt = 0; jt < 32; ++jt) {
      float e = __expf(acc[jt][r] - rmax[r]);
      acc[jt][r] = e;
      sum += e;
    }
#pragma unroll
    for (int d = 1; d < 16; d <<= 1) sum += __shfl_xor(sum, d, 64);
    rinv[r] = 1.0f / sum;
  }
#pragma unroll
  for (int r = 0; r < 4; ++r) {
    int tl = 16 * w + quad * 4 + r;
    size_t base = (((size_t)h * BB + b) * TT + (t0 + tl)) * TT;
#pragma unroll
    for (int jt = 0; jt < 32; ++jt) out[base + jt * 16 + nl] = acc[jt][r] * rinv[r];
  }
}

extern "C" void kernel_launch(void* const* d_in, const int* in_sizes, int n_in,
                              void* d_out, int out_size, void* d_ws, size_t ws_size,
                              hipStream_t stream) {
  const float* lm = (const float*)d_in[0];
  const float* am = (const float*)d_in[1];
  const float* pos_emb = (const float*)d_in[2];
  const unsigned char* mask = (const unsigned char*)d_in[3];
  const float* Wlm = (const float*)d_in[4];
  const float* blm = (const float*)d_in[5];
  const float* Wam = (const float*)d_in[6];
  const float* bam = (const float*)d_in[7];
  const float* Wpos = (const float*)d_in[8];
  float* out = (float*)d_out;

  // workspace layout (~24 MB)
  char* ws = (char*)d_ws;
  __bf16* qbuf = (__bf16*)ws;                       // 32768*160 bf16
  __bf16* kbuf = qbuf + (size_t)32768 * 160;        // 32768*160 bf16
  float* pbuf = (float*)(kbuf + (size_t)32768 * 160);  // 32768*20 f32
  float* pebuf = pbuf + (size_t)32768 * 20;         // 5*1023*4 f32
  __bf16* WlmT = (__bf16*)(pebuf + (size_t)5 * NPOS * 4);  // 192*512
  __bf16* WamT = WlmT + (size_t)192 * 512;          // 160*512

  prep_w_kernel<<<384, 256, 0, stream>>>(Wlm, Wam, WlmT, WamT);
  pe_proj_kernel<<<NPOS, 64, 0, stream>>>(pos_emb, Wpos, pebuf);
  proj_kernel<12, true><<<512, 256, 0, stream>>>(lm, WlmT, blm, qbuf, pbuf);
  proj_kernel<10, false><<<512, 256, 0, stream>>>(am, WamT, bam, kbuf, nullptr);
  attn_kernel<<<dim3(8, BB, HH), 256, 0, stream>>>(qbuf, kbuf, pbuf, pebuf, mask, out);
}

// Round 2
// 511.339 us; speedup vs baseline: 1.0671x; 1.0671x over previous
//
#include <hip/hip_runtime.h>

#define TT 512
#define BB 64
#define HH 5
#define NPOS 1023  // 2T-1

typedef __bf16 bf16x8 __attribute__((ext_vector_type(8)));
typedef __bf16 bf16x4 __attribute__((ext_vector_type(4)));
typedef float floatx4 __attribute__((ext_vector_type(4)));

// ---------- prep: W transpose->bf16 (blocks 0..383) + pe projection (blocks 384..511) ----------
__global__ void prep_kernel(const float* __restrict__ Wlm, const float* __restrict__ Wam,
                            const float* __restrict__ pos_emb, const float* __restrict__ Wpos,
                            __bf16* __restrict__ WlmT, __bf16* __restrict__ WamT,
                            __bf16* __restrict__ peB) {
  int bx = blockIdx.x;
  if (bx < 384) {
    int idx = bx * 256 + threadIdx.x;
    if (idx < 192 * 512) {
      int n = idx >> 9, k = idx & 511;
      float v = (n < 180) ? Wlm[k * 180 + n] : 0.f;
      WlmT[idx] = (__bf16)v;
    }
    if (idx < 160 * 512) {
      int n = idx >> 9, k = idx & 511;
      WamT[idx] = (__bf16)Wam[k * 160 + n];
    }
  } else {
    int t = (bx - 384) * 256 + threadIdx.x;  // [0, 32768)
    int n = t >> 5, c = t & 31;
    if (n < NPOS && c < 20) {
      float acc = 0.f;
#pragma unroll 8
      for (int pd = 0; pd < 192; ++pd) acc += pos_emb[n * 192 + pd] * Wpos[pd * 20 + c];
      int h = c >> 2, d = c & 3;
      peB[((size_t)h * NPOS + n) * 4 + d] = (__bf16)acc;
    }
  }
}

// ---------- projection GEMMs: (32768 x 512) @ (512 x NT*16), lm and am merged ----------
template <int NT, bool IS_LM>
__device__ __forceinline__ void proj_body(const float* __restrict__ A, const __bf16* __restrict__ WT,
                                          const float* __restrict__ bias, __bf16* __restrict__ qk_out,
                                          float* __restrict__ p_out, int blk,
                                          __bf16 (*a_lds)[32], __bf16 (*w_lds)[32]) {
  const int tid = threadIdx.x;
  const int m0 = blk * 64;
  const int lane = tid & 63, w = tid >> 6;
  const int quad = lane >> 4, nl = lane & 15;

  floatx4 acc[NT];
#pragma unroll
  for (int j = 0; j < NT; ++j) acc[j] = floatx4{0.f, 0.f, 0.f, 0.f};

  const int arow = tid >> 2, aseg = tid & 3;
  for (int k0 = 0; k0 < 512; k0 += 32) {
    const float* ap = A + (size_t)(m0 + arow) * 512 + k0 + aseg * 8;
    float4 av0 = *(const float4*)ap;
    float4 av1 = *(const float4*)(ap + 4);
    bf16x8 pk;
    pk[0] = (__bf16)av0.x; pk[1] = (__bf16)av0.y; pk[2] = (__bf16)av0.z; pk[3] = (__bf16)av0.w;
    pk[4] = (__bf16)av1.x; pk[5] = (__bf16)av1.y; pk[6] = (__bf16)av1.z; pk[7] = (__bf16)av1.w;
    *(bf16x8*)&a_lds[arow][aseg * 8] = pk;
#pragma unroll
    for (int task = tid; task < NT * 64; task += 256) {
      int n = task >> 2, seg = task & 3;
      *(bf16x8*)&w_lds[n][seg * 8] = *(const bf16x8*)(WT + (size_t)n * 512 + k0 + seg * 8);
    }
    __syncthreads();
    bf16x8 afr = *(const bf16x8*)&a_lds[16 * w + nl][quad * 8];
#pragma unroll
    for (int jt = 0; jt < NT; ++jt) {
      bf16x8 bfr = *(const bf16x8*)&w_lds[jt * 16 + nl][quad * 8];
      acc[jt] = __builtin_amdgcn_mfma_f32_16x16x32_bf16(afr, bfr, acc[jt], 0, 0, 0);
    }
    __syncthreads();
  }
#pragma unroll
  for (int jt = 0; jt < NT; ++jt) {
    int c = jt * 16 + nl;
#pragma unroll
    for (int r = 0; r < 4; ++r) {
      int m = m0 + 16 * w + quad * 4 + r;
      float bv = IS_LM ? ((c < 180) ? bias[c] : 0.f) : bias[c];
      float val = acc[jt][r] + bv;
      if (IS_LM) {
        if (c < 160) qk_out[(size_t)m * 160 + c] = (__bf16)val;
        else if (c < 180) p_out[(size_t)m * 20 + (c - 160)] = val;
      } else {
        qk_out[(size_t)m * 160 + c] = (__bf16)val;
      }
    }
  }
}

__global__ __launch_bounds__(256, 4) void proj_kernel(
    const float* __restrict__ lm, const __bf16* __restrict__ WlmT, const float* __restrict__ blm,
    __bf16* __restrict__ qbuf, float* __restrict__ pbuf,
    const float* __restrict__ am, const __bf16* __restrict__ WamT, const float* __restrict__ bam,
    __bf16* __restrict__ kbuf) {
  __shared__ __align__(16) __bf16 a_lds[64][32];
  __shared__ __align__(16) __bf16 w_lds[192][32];
  if (blockIdx.x < 512)
    proj_body<12, true>(lm, WlmT, blm, qbuf, pbuf, blockIdx.x, a_lds, w_lds);
  else
    proj_body<10, false>(am, WamT, bam, kbuf, nullptr, blockIdx.x - 512, a_lds, w_lds);
}

// ---------- fused scores + rel-shift + mask + softmax ----------
// grid (8, 64, 5); block 256 = 4 waves; each wave: 16 rows x 512 cols row-resident.
__global__ __launch_bounds__(256, 2) void attn_kernel(
    const __bf16* __restrict__ q, const __bf16* __restrict__ k,
    const float* __restrict__ p, const __bf16* __restrict__ peB,
    const unsigned char* __restrict__ mask, float* __restrict__ out) {
  __shared__ __align__(16) __bf16 k_lds[512][32];
  __shared__ __align__(16) __bf16 q_lds[64][32];
  __shared__ __align__(16) float p_lds[64][4];
  __shared__ __align__(16) __bf16 pe_lds[576 * 4];  // bf16x4 per window index
  __shared__ float mask_lds[512];

  const int tid = threadIdx.x;
  const int t0 = blockIdx.x * 64;
  const int b = blockIdx.y;
  const int h = blockIdx.z;
  const int lane = tid & 63, w = tid >> 6;
  const int quad = lane >> 4, nl = lane & 15;

#pragma unroll
  for (int it = 0; it < 8; ++it) {
    int idx = tid + it * 256;
    int s = idx >> 2, c = idx & 3;
    *(bf16x8*)&k_lds[s][c * 8] =
        *(const bf16x8*)(k + (size_t)(s * BB + b) * 160 + h * 32 + c * 8);
  }
  {
    int s = tid >> 2, c = tid & 3;
    *(bf16x8*)&q_lds[s][c * 8] =
        *(const bf16x8*)(q + (size_t)((t0 + s) * BB + b) * 160 + h * 32 + c * 8);
  }
  if (tid < 64)
    *(float4*)&p_lds[tid][0] = *(const float4*)(p + (size_t)((t0 + tid) * BB + b) * 20 + h * 4);
  {
    int u0 = 448 - t0;  // window start in global u; i in [0,575)
    for (int i = tid; i < 575; i += 256)
      *(bf16x4*)&pe_lds[i * 4] = *(const bf16x4*)(peB + ((size_t)h * NPOS + u0 + i) * 4);
  }
  for (int i = tid; i < 512; i += 256)
    mask_lds[i] = mask[b * 512 + i] ? -1000.f : 0.f;
  __syncthreads();

  // content scores via MFMA, mask folded into C-init
  floatx4 acc[32];
  bf16x8 af = *(const bf16x8*)&q_lds[16 * w + nl][quad * 8];
#pragma unroll
  for (int jt = 0; jt < 32; ++jt) {
    float m = mask_lds[jt * 16 + nl];
    floatx4 cin = {m, m, m, m};
    bf16x8 bfr = *(const bf16x8*)&k_lds[jt * 16 + nl][quad * 8];
    acc[jt] = __builtin_amdgcn_mfma_f32_16x16x32_bf16(af, bfr, cin, 0, 0, 0);
  }

  // pos scores: per (jt), the 4 rows read 8 consecutive u32 words of bf16 pe
  const int base = 16 * w + quad * 4;
  floatx4 pv[4];
#pragma unroll
  for (int r = 0; r < 4; ++r) pv[r] = *(const floatx4*)&p_lds[base + r][0];

  const uint32_t* pp = (const uint32_t*)pe_lds + 2 * (nl - base + 63);
  float mx[4] = {-3.4e38f, -3.4e38f, -3.4e38f, -3.4e38f};
#pragma unroll
  for (int jt = 0; jt < 32; ++jt) {
    const uint32_t* pj = pp + jt * 32;
#pragma unroll
    for (int r = 0; r < 4; ++r) {
      uint32_t w0 = pj[-2 * r], w1 = pj[1 - 2 * r];
      float f0 = __uint_as_float(w0 << 16);
      float f1 = __uint_as_float(w0 & 0xffff0000u);
      float f2 = __uint_as_float(w1 << 16);
      float f3 = __uint_as_float(w1 & 0xffff0000u);
      float v = acc[jt][r];
      v = fmaf(pv[r][0], f0, v);
      v = fmaf(pv[r][1], f1, v);
      v = fmaf(pv[r][2], f2, v);
      v = fmaf(pv[r][3], f3, v);
      acc[jt][r] = v;
      mx[r] = fmaxf(mx[r], v);
    }
  }

#pragma unroll
  for (int r = 0; r < 4; ++r) {
#pragma unroll
    for (int d = 1; d < 16; d <<= 1) mx[r] = fmaxf(mx[r], __shfl_xor(mx[r], d, 64));
  }
  float rinv[4];
#pragma unroll
  for (int r = 0; r < 4; ++r) {
    float sum = 0.f;
#pragma unroll
    for (int jt = 0; jt < 32; ++jt) {
      float e = __expf(acc[jt][r] - mx[r]);
      acc[jt][r] = e;
      sum += e;
    }
#pragma unroll
    for (int d = 1; d < 16; d <<= 1) sum += __shfl_xor(sum, d, 64);
    rinv[r] = 1.0f / sum;
  }
#pragma unroll
  for (int r = 0; r < 4; ++r) {
    size_t basep = (((size_t)h * BB + b) * TT + (t0 + base + r)) * TT;
#pragma unroll
    for (int jt = 0; jt < 32; ++jt) out[basep + jt * 16 + nl] = acc[jt][r] * rinv[r];
  }
}

extern "C" void kernel_launch(void* const* d_in, const int* in_sizes, int n_in,
                              void* d_out, int out_size, void* d_ws, size_t ws_size,
                              hipStream_t stream) {
  const float* lm = (const float*)d_in[0];
  const float* am = (const float*)d_in[1];
  const float* pos_emb = (const float*)d_in[2];
  const unsigned char* mask = (const unsigned char*)d_in[3];
  const float* Wlm = (const float*)d_in[4];
  const float* blm = (const float*)d_in[5];
  const float* Wam = (const float*)d_in[6];
  const float* bam = (const float*)d_in[7];
  const float* Wpos = (const float*)d_in[8];
  float* out = (float*)d_out;

  char* ws = (char*)d_ws;
  __bf16* qbuf = (__bf16*)ws;                          // 32768*160 bf16
  __bf16* kbuf = qbuf + (size_t)32768 * 160;           // 32768*160 bf16
  float* pbuf = (float*)(kbuf + (size_t)32768 * 160);  // 32768*20 f32
  __bf16* peB = (__bf16*)(pbuf + (size_t)32768 * 20);  // 5*1024*4 bf16 (padded alloc)
  __bf16* WlmT = peB + (size_t)5 * 1024 * 4;           // 192*512
  __bf16* WamT = WlmT + (size_t)192 * 512;             // 160*512

  prep_kernel<<<512, 256, 0, stream>>>(Wlm, Wam, pos_emb, Wpos, WlmT, WamT, peB);
  proj_kernel<<<1024, 256, 0, stream>>>(lm, WlmT, blm, qbuf, pbuf, am, WamT, bam, kbuf);
  attn_kernel<<<dim3(8, BB, HH), 256, 0, stream>>>(qbuf, kbuf, pbuf, peB, mask, out);
}